// Round 2
// baseline (545.725 us; speedup 1.0000x reference)
//
#include <hip/hip_runtime.h>
#include <stdint.h>

typedef unsigned short u16;
typedef __attribute__((ext_vector_type(8))) short bf16x8;   // 8 bf16 = 4 VGPR
typedef __attribute__((ext_vector_type(4))) float f32x4;
typedef __attribute__((ext_vector_type(4))) u16 u16x4;
typedef __attribute__((ext_vector_type(8))) u16 u16x8;

#define ALPHA 0.08838834764831845f   // 1/sqrt(128)

__device__ __forceinline__ u16 f2bf(float f){
  union { float f; uint32_t i; } x; x.f = f;
  uint32_t r = (x.i + 0x7FFFu + ((x.i >> 16) & 1u)) >> 16;
  return (u16)r;
}
// async global->LDS, 16B per lane; LDS dest wave-uniform base (+lane*16 implicit)
__device__ __forceinline__ void gld16(const void* g, void* l){
  __builtin_amdgcn_global_load_lds((const __attribute__((address_space(1))) void*)g,
                                   (__attribute__((address_space(3))) void*)l, 16, 0, 0);
}

// ---------------------------------------------------------------------------
// fp32 -> bf16 cast, 8 elems/thread
// ---------------------------------------------------------------------------
__global__ __launch_bounds__(256)
void cast_f32_bf16(const float* __restrict__ src, u16* __restrict__ dst, int n){
  const int i = (blockIdx.x * 256 + threadIdx.x) * 8;
  if (i >= n) return;
  const float4 a = *(const float4*)(src + i);
  const float4 b = *(const float4*)(src + i + 4);
  u16x8 o;
  o[0]=f2bf(a.x); o[1]=f2bf(a.y); o[2]=f2bf(a.z); o[3]=f2bf(a.w);
  o[4]=f2bf(b.x); o[5]=f2bf(b.y); o[6]=f2bf(b.z); o[7]=f2bf(b.w);
  *(u16x8*)(dst + i) = o;
}

// ---------------------------------------------------------------------------
// fp32 -> bf16 tiled transpose: dst[C][R] = bf16(src[R][C]^T)
// ---------------------------------------------------------------------------
__global__ __launch_bounds__(256)
void transpose_f32_bf16(const float* __restrict__ src, u16* __restrict__ dst, int R, int C){
  __shared__ u16 tile[32][33];
  const int c0 = blockIdx.x * 32, r0 = blockIdx.y * 32;
  const int tc = threadIdx.x & 31, tr = threadIdx.x >> 5;   // 32 cols x 8 rows
#pragma unroll
  for(int i = 0; i < 4; i++)
    tile[tr + i*8][tc] = f2bf(src[(size_t)(r0 + tr + i*8) * C + c0 + tc]);
  __syncthreads();
#pragma unroll
  for(int i = 0; i < 4; i++)
    dst[(size_t)(c0 + tr + i*8) * R + r0 + tc] = tile[tc][tr + i*8];
}

// ---------------------------------------------------------------------------
// GEMM: C[M][N] = A[M][K] @ Bt[N][K]^T
// EPI0: C=bf16 qkv (+bias), V-part scattered transposed into Vt[bh][d][s]
// EPI1: C=fp32 out = acc + bias + residual
// 128x128 tile, BK=32, 4 waves (2x2), wave = 64x64 = 4x4 frags of 16x16x32.
// LDS linear (global_load_lds), XOR swizzle via pre-swizzled global source.
// ---------------------------------------------------------------------------
template<int EPI>
__global__ __launch_bounds__(256)
void gemm_bt(const u16* __restrict__ A, const u16* __restrict__ Bt,
             const float* __restrict__ bias, const float* __restrict__ resid,
             u16* __restrict__ Cb, float* __restrict__ Cf,
             u16* __restrict__ Vt, int K, int ldc)
{
  __shared__ u16 As[128*32];
  __shared__ u16 Bs[128*32];
  const int t  = threadIdx.x;
  const int w  = t >> 6, l = t & 63;
  const int wr = w >> 1, wc = w & 1;
  const int lr = l & 15, lg = l >> 4;
  const int m0 = blockIdx.x * 128, n0 = blockIdx.y * 128;

  f32x4 acc[4][4];
#pragma unroll
  for(int i = 0; i < 4; i++)
#pragma unroll
    for(int j = 0; j < 4; j++) acc[i][j] = (f32x4){0.f,0.f,0.f,0.f};

  for(int k0 = 0; k0 < K; k0 += 32){
#pragma unroll
    for(int r = 0; r < 2; r++){
      const int o   = r*256 + t;             // octet id within 128x4-octet tile
      const int row = o >> 2;
      const int oc  = (o & 3) ^ (row & 3);   // inverse-swizzled source octet
      gld16(A  + (size_t)(m0 + row) * K + k0 + oc*8, (void*)(As + (r*256 + w*64)*8));
      gld16(Bt + (size_t)(n0 + row) * K + k0 + oc*8, (void*)(Bs + (r*256 + w*64)*8));
    }
    __syncthreads();
    bf16x8 af[4], bfr[4];
#pragma unroll
    for(int i = 0; i < 4; i++){
      const int ra = wr*64 + i*16 + lr;
      af[i] = *(const bf16x8*)(As + ra*32 + ((lg ^ (ra & 3)) * 8));
      const int rb = wc*64 + i*16 + lr;
      bfr[i] = *(const bf16x8*)(Bs + rb*32 + ((lg ^ (rb & 3)) * 8));
    }
#pragma unroll
    for(int i = 0; i < 4; i++)
#pragma unroll
      for(int j = 0; j < 4; j++)
        acc[i][j] = __builtin_amdgcn_mfma_f32_16x16x32_bf16(af[i], bfr[j], acc[i][j], 0, 0, 0);
    __syncthreads();
  }

  // epilogue: C/D frag layout col = lane&15, row = (lane>>4)*4 + r
#pragma unroll
  for(int i = 0; i < 4; i++){
#pragma unroll
    for(int j = 0; j < 4; j++){
      const int row = m0 + wr*64 + i*16 + lg*4;
      const int col = n0 + wc*64 + j*16 + lr;
      const float bia = bias[col];
      if (EPI == 0){
        const int hh = col / 384, rem = col - hh*384;    // head, which*128+d
        if (rem < 256){                                   // K (rem<128) or Q
#pragma unroll
          for(int r = 0; r < 4; r++)
            Cb[(size_t)(row + r) * ldc + col] = f2bf(acc[i][j][r] + bia);
        } else {                                          // V -> transposed Vt[bh][d][s]
          const int d = rem - 256;
          const int b = row >> 11, s = row & 2047;        // rows 4-aligned: same b
          u16x4 pk;
#pragma unroll
          for(int r = 0; r < 4; r++) pk[r] = f2bf(acc[i][j][r] + bia);
          *(u16x4*)(Vt + (size_t)((b*16 + hh)*128 + d) * 2048 + s) = pk;
        }
      } else {
#pragma unroll
        for(int r = 0; r < 4; r++){
          const size_t idx = (size_t)(row + r) * ldc + col;
          Cf[idx] = acc[i][j][r] + bia + resid[idx];
        }
      }
    }
  }
}

// ---------------------------------------------------------------------------
// Flash attention, causal + ALiBi. 1 block = (bh, 64 q-rows), 4 waves x 16 rows.
// qkv layout [B*S][6144]: col = (h*3+which)*128+d, which: 0=K 1=Q 2=V.
// VtG layout [bh][d][s] (transposed by gemm1 epilogue).
// ---------------------------------------------------------------------------
__global__ __launch_bounds__(256)
void attn_fwd(const u16* __restrict__ qkv, const u16* __restrict__ VtG,
              const float* __restrict__ alibi, u16* __restrict__ ctx)
{
  __shared__ u16 Qs[64*128];
  __shared__ u16 Ks[64*128];
  __shared__ u16 Vs[128*64];      // Vt tile: [d][k]
  __shared__ u16 Ps[4][16*64];    // per-wave P (swizzled)

  const int qt = blockIdx.x, bh = blockIdx.y;
  const int b = bh >> 4, h = bh & 15;
  const int t = threadIdx.x, w = t >> 6, l = t & 63;
  const int lr = l & 15, lg = l >> 4;

  // stage Q tile [64][128] (swizzled source, linear LDS)
  const size_t qbase = (size_t)(b*2048 + qt*64) * 6144 + (h*3 + 1) * 128;
#pragma unroll
  for(int r = 0; r < 4; r++){
    const int o = r*256 + t;
    const int row = o >> 4, oc = (o & 15) ^ (row & 7);
    gld16(qkv + qbase + (size_t)row * 6144 + oc*8, (void*)(Qs + (r*256 + w*64)*8));
  }

  float mr[4], lsum[4];
  f32x4 oa[8];
#pragma unroll
  for(int r = 0; r < 4; r++){ mr[r] = -1e30f; lsum[r] = 0.f; }
#pragma unroll
  for(int d = 0; d < 8; d++) oa[d] = (f32x4){0.f,0.f,0.f,0.f};

  const size_t kbase = (size_t)(b*2048) * 6144 + (h*3) * 128;
  const size_t vbase = (size_t)(bh*128) * 2048;

  for(int kt = 0; kt <= qt; ++kt){
    __syncthreads();   // prev iteration's LDS reads done everywhere
#pragma unroll
    for(int r = 0; r < 4; r++){
      const int o = r*256 + t;
      const int row = o >> 4, oc = (o & 15) ^ (row & 7);
      gld16(qkv + kbase + (size_t)(kt*64 + row) * 6144 + oc*8, (void*)(Ks + (r*256 + w*64)*8));
    }
#pragma unroll
    for(int r = 0; r < 4; r++){
      const int o = r*256 + t;
      const int row = o >> 3, oc = (o & 7) ^ (row & 7);
      gld16(VtG + vbase + (size_t)row * 2048 + kt*64 + oc*8, (void*)(Vs + (r*256 + w*64)*8));
    }
    __syncthreads();   // drains vmcnt -> tiles visible (covers Q on first iter)

    // S = Q K^T  (M=16 q-rows of this wave, N=64 k-cols, K=128)
    f32x4 sa[4];
#pragma unroll
    for(int j = 0; j < 4; j++) sa[j] = (f32x4){0.f,0.f,0.f,0.f};
#pragma unroll
    for(int ko = 0; ko < 4; ko++){
      const int rq = w*16 + lr;
      const bf16x8 aq = *(const bf16x8*)(Qs + rq*128 + (((ko*4 + lg) ^ (rq & 7)) * 8));
#pragma unroll
      for(int j = 0; j < 4; j++){
        const int rk = j*16 + lr;
        const bf16x8 bk = *(const bf16x8*)(Ks + rk*128 + (((ko*4 + lg) ^ (rk & 7)) * 8));
        sa[j] = __builtin_amdgcn_mfma_f32_16x16x32_bf16(aq, bk, sa[j], 0, 0, 0);
      }
    }

    // ALiBi bias (depends on k only)
    float ali[4];
#pragma unroll
    for(int j = 0; j < 4; j++) ali[j] = alibi[bh*2048 + kt*64 + j*16 + lr];

    // online softmax; C/D layout: row=(lg*4+r), col=lr within each 16x16 frag
#pragma unroll
    for(int r = 0; r < 4; r++){
      const int qrow = qt*64 + w*16 + lg*4 + r;
      float sv[4]; float tm = -1e30f;
#pragma unroll
      for(int j = 0; j < 4; j++){
        const int kc = kt*64 + j*16 + lr;
        float s = sa[j][r] * ALPHA + ali[j];
        s = (kc > qrow) ? -1e30f : s;
        sv[j] = s; tm = fmaxf(tm, s);
      }
      tm = fmaxf(tm, __shfl_xor(tm, 1));
      tm = fmaxf(tm, __shfl_xor(tm, 2));
      tm = fmaxf(tm, __shfl_xor(tm, 4));
      tm = fmaxf(tm, __shfl_xor(tm, 8));
      const float mn = fmaxf(mr[r], tm);
      const float sc = __expf(mr[r] - mn);
      float ps = 0.f;
#pragma unroll
      for(int j = 0; j < 4; j++){
        const float p = __expf(sv[j] - mn);
        ps += p;
        const int rr = lg*4 + r;
        Ps[w][rr*64 + ((j*16 + lr) ^ ((rr & 7) << 3))] = f2bf(p);
      }
      ps += __shfl_xor(ps, 1);
      ps += __shfl_xor(ps, 2);
      ps += __shfl_xor(ps, 4);
      ps += __shfl_xor(ps, 8);
      lsum[r] = lsum[r] * sc + ps;
      mr[r] = mn;
#pragma unroll
      for(int d = 0; d < 8; d++) oa[d][r] *= sc;   // rescale O rows
    }

    // O += P @ V   (A = P[16 q][64 k], B cols = Vs rows [d][k]; per-wave Ps)
#pragma unroll
    for(int ko = 0; ko < 2; ko++){
      const bf16x8 ap = *(const bf16x8*)(&Ps[w][lr*64 + (((ko*4 + lg) ^ (lr & 7)) * 8)]);
#pragma unroll
      for(int d = 0; d < 8; d++){
        const int rv = d*16 + lr;
        const bf16x8 bv = *(const bf16x8*)(Vs + rv*64 + (((ko*4 + lg) ^ (rv & 7)) * 8));
        oa[d] = __builtin_amdgcn_mfma_f32_16x16x32_bf16(ap, bv, oa[d], 0, 0, 0);
      }
    }
  }

  // write ctx (bf16) in merged-head layout [b, s, h*128+d]
#pragma unroll
  for(int d = 0; d < 8; d++){
#pragma unroll
    for(int r = 0; r < 4; r++){
      const int s = qt*64 + w*16 + lg*4 + r;
      ctx[(size_t)(b*2048 + s) * 2048 + h*128 + d*16 + lr] = f2bf(oa[d][r] / lsum[r]);
    }
  }
}

// ---------------------------------------------------------------------------
extern "C" void kernel_launch(void* const* d_in, const int* in_sizes, int n_in,
                              void* d_out, int out_size, void* d_ws, size_t ws_size,
                              hipStream_t stream) {
  const float* hid   = (const float*)d_in[0];
  // d_in[1] = attention_mask (bool causal) -- recomputed analytically, unused
  const float* resid = (const float*)d_in[2];
  const float* alibi = (const float*)d_in[3];
  const float* Wqkv  = (const float*)d_in[4];
  const float* bqkv  = (const float*)d_in[5];
  const float* Wd    = (const float*)d_in[6];
  const float* bd    = (const float*)d_in[7];
  float* out = (float*)d_out;

  char* ws = (char*)d_ws;
  u16* qkv  = (u16*)(ws);                  // [4096][6144] bf16   50331648 B
  u16* Vt   = (u16*)(ws +  50331648);      // [32][128][2048]     16777216 B
  u16* ctx  = (u16*)(ws +  67108864);      // [4096][2048]        16777216 B
  u16* hidB = (u16*)(ws +  83886080);      // [4096][2048]        16777216 B
  u16* WqT  = (u16*)(ws + 100663296);      // [6144][2048]        25165824 B
  u16* WdT  = (u16*)(ws + 125829120);      // [2048][2048]         8388608 B

  cast_f32_bf16<<<dim3(4096), 256, 0, stream>>>(hid, hidB, 4096*2048);
  transpose_f32_bf16<<<dim3(192, 64), 256, 0, stream>>>(Wqkv, WqT, 2048, 6144);
  transpose_f32_bf16<<<dim3( 64, 64), 256, 0, stream>>>(Wd,   WdT, 2048, 2048);

  gemm_bt<0><<<dim3(32, 48), 256, 0, stream>>>(hidB, WqT, bqkv, nullptr, qkv, nullptr, Vt, 2048, 6144);

  attn_fwd<<<dim3(32, 32), 256, 0, stream>>>(qkv, Vt, alibi, ctx);

  gemm_bt<1><<<dim3(32, 16), 256, 0, stream>>>(ctx, WdT, bd, resid, nullptr, out, nullptr, 2048, 2048);
}